// Round 10
// baseline (235.575 us; speedup 1.0000x reference)
//
#include <hip/hip_runtime.h>
#include <hip/hip_bf16.h>

#define EF 128
#define KNN 8

typedef __attribute__((ext_vector_type(8)))  short          short8;
typedef __attribute__((ext_vector_type(8)))  unsigned short ushort8;
typedef __attribute__((ext_vector_type(4)))  float          f32x4;
typedef __attribute__((ext_vector_type(16))) float          f32x16;

// software round-to-nearest-even f32 -> bf16 bits (cold paths)
static __device__ __forceinline__ unsigned short f2bf(float f) {
    unsigned int x = __float_as_uint(f);
    unsigned int r = x + 0x7fffu + ((x >> 16) & 1u);
    return (unsigned short)(r >> 16);
}
// sanctioned compiler conversion (RNE) for hot paths
static __device__ __forceinline__ short f2bf_hw(float f) {
    return (short)__bfloat16_as_ushort(__float2bfloat16(f));
}

// ---------------------------------------------------------------------------
// pack_kernel:
//   W1[:128] -> W1p, 32x32x16 B-frag order (zgemm):
//     s = (((kt*4+nt)*64+l)*8+j); k = kt*16+(l>>5)*8+j; n = nt*32+(l&31)
//   W2      -> W2p, 16x16x32 B-frag order (edge kernel):
//     s = (((kt*8+nt)*64+l)*8+j); k = kt*32+(l>>4)*8+j; n = nt*16+(l&15)
// ---------------------------------------------------------------------------
__global__ __launch_bounds__(256) void pack_kernel(
    const float* __restrict__ W1, const float* __restrict__ W2,
    unsigned short* __restrict__ W1p, unsigned short* __restrict__ W2p)
{
    int t = blockIdx.x * 256 + threadIdx.x;
    if (t < 16384) {
        int s = t;
        int j  = s & 7;
        int l  = (s >> 3) & 63;
        int nt = (s >> 9) & 3;
        int kt = (s >> 11) & 7;
        int k = kt * 16 + (l >> 5) * 8 + j;
        int n = nt * 32 + (l & 31);
        W1p[s] = f2bf(W1[k * EF + n]);
    } else if (t < 32768) {
        int s = t - 16384;
        int j  = s & 7;
        int l  = (s >> 3) & 63;
        int nt = (s >> 9) & 7;
        int kt = (s >> 12) & 3;
        int k = kt * 32 + (l >> 4) * 8 + j;
        int n = nt * 16 + (l & 15);
        W2p[s] = f2bf(W2[k * EF + n]);
    }
}

// ---------------------------------------------------------------------------
// zgemm_kernel: Z[p][d] = bf16( b1[d] + sum_k input[p][k] * W1[k][d] )
// (unchanged 32x32x16 structure, verified rounds 2/5/7/8/9)
// ---------------------------------------------------------------------------
__global__ __launch_bounds__(256) void zgemm_kernel(
    const float* __restrict__ input,
    const unsigned short* __restrict__ W1p,
    const float* __restrict__ b1,
    unsigned short* __restrict__ Z,
    int npts, int ntiles)
{
    int l = threadIdx.x & 63;
    int tile = blockIdx.x * 4 + (threadIdx.x >> 6);
    if (tile >= ntiles) return;
    int p0   = tile * 32;
    int r    = l & 31;
    int half = l >> 5;
    int prow = p0 + r;
    if (prow >= npts) prow = npts - 1;      // clamp for ragged tail (reads only)
    const float* Arow = input + (size_t)prow * EF;

    f32x16 acc[4];
#pragma unroll
    for (int nt = 0; nt < 4; ++nt)
#pragma unroll
        for (int i = 0; i < 16; ++i) acc[nt][i] = 0.f;

#pragma unroll
    for (int kt = 0; kt < 8; ++kt) {
        int k0 = kt * 16 + half * 8;
        float4 a0 = *(const float4*)(Arow + k0);
        float4 a1 = *(const float4*)(Arow + k0 + 4);
        short8 a;
        a[0] = f2bf_hw(a0.x); a[1] = f2bf_hw(a0.y);
        a[2] = f2bf_hw(a0.z); a[3] = f2bf_hw(a0.w);
        a[4] = f2bf_hw(a1.x); a[5] = f2bf_hw(a1.y);
        a[6] = f2bf_hw(a1.z); a[7] = f2bf_hw(a1.w);
#pragma unroll
        for (int nt = 0; nt < 4; ++nt) {
            short8 b = *(const short8*)(W1p + ((size_t)((kt * 4 + nt) * 64 + l)) * 8);
            acc[nt] = __builtin_amdgcn_mfma_f32_32x32x16_bf16(a, b, acc[nt], 0, 0, 0);
        }
    }

    int col = l & 31;
#pragma unroll
    for (int nt = 0; nt < 4; ++nt) {
        float bb = b1[nt * 32 + col];
#pragma unroll
        for (int reg = 0; reg < 16; ++reg) {
            int row = (reg & 3) + 8 * (reg >> 2) + 4 * half;
            int p = p0 + row;
            if (p < npts)
                Z[(size_t)p * EF + nt * 32 + col] = f2bf(acc[nt][reg] + bb);
        }
    }
}

// ---------------------------------------------------------------------------
// edge_mfma_kernel (16x16x32): PERSISTENT waves, each grid-striding over
// 16-edge tiles (= 2 points each). W2 staged to LDS once per block.
// Double-buffered register gather pipeline: while computing tile t, the
// loads for tile t+stride are in flight.
// ---------------------------------------------------------------------------
__global__ __launch_bounds__(512) void edge_mfma_kernel(
    const unsigned short* __restrict__ Z,
    const int* __restrict__ knn_idx,
    const float* __restrict__ knn_xyz,
    const unsigned short* __restrict__ W2p,
    const float* __restrict__ W1,       // xyz rows at +128*EF (f32)
    const float* __restrict__ b2,
    float* __restrict__ out,
    int npts, int nedges, int ntiles)
{
    __shared__ short8 w2lds[2048];      // 32 KB: full packed W2, frag order
    __shared__ float  wlds[3 * EF];     // W1 rows 128..130, f32

    // ---- stage W2 fragments + xyz weights into LDS (once per block) -------
    {
        const short8* W2v = (const short8*)W2p;
#pragma unroll
        for (int i = threadIdx.x; i < 2048; i += 512)
            w2lds[i] = W2v[i];
        for (int t = threadIdx.x; t < 3 * EF; t += 512)
            wlds[t] = W1[EF * EF + t];
    }
    __syncthreads();

    int l  = threadIdx.x & 63;
    int r  = l & 15;                    // edge row within tile
    int hi = l >> 4;                    // k-group 0..3
    int wid    = blockIdx.x * 8 + (threadIdx.x >> 6);
    int stride = gridDim.x * 8;

    ushort8 zvA[4], zvB[4];
    float xA, yA, zA, xB, yB, zB;

    auto fetch = [&](int tile, ushort8 (&zv)[4], float& x, float& y, float& z) {
        int edge = tile * 16 + r;
        if (edge >= nedges) edge = nedges - 1;   // clamp (reads only)
        int idx = knn_idx[edge];
        x = knn_xyz[edge * 3 + 0];
        y = knn_xyz[edge * 3 + 1];
        z = knn_xyz[edge * 3 + 2];
        const unsigned short* Zrow = Z + (size_t)idx * EF;
#pragma unroll
        for (int kt = 0; kt < 4; ++kt)
            zv[kt] = *(const ushort8*)(Zrow + kt * 32 + hi * 8);
    };

    auto compute = [&](int tile, const ushort8 (&zv)[4],
                       float x, float y, float z) {
        f32x4 acc[8];
#pragma unroll
        for (int nt = 0; nt < 8; ++nt)
#pragma unroll
            for (int i = 0; i < 4; ++i) acc[nt][i] = 0.f;

#pragma unroll
        for (int kt = 0; kt < 4; ++kt) {
            int d0 = kt * 32 + hi * 8;
            float4 wx0 = *(const float4*)&wlds[0 * EF + d0];
            float4 wx1 = *(const float4*)&wlds[0 * EF + d0 + 4];
            float4 wy0 = *(const float4*)&wlds[1 * EF + d0];
            float4 wy1 = *(const float4*)&wlds[1 * EF + d0 + 4];
            float4 wz0 = *(const float4*)&wlds[2 * EF + d0];
            float4 wz1 = *(const float4*)&wlds[2 * EF + d0 + 4];
            float wxa[8] = {wx0.x, wx0.y, wx0.z, wx0.w, wx1.x, wx1.y, wx1.z, wx1.w};
            float wya[8] = {wy0.x, wy0.y, wy0.z, wy0.w, wy1.x, wy1.y, wy1.z, wy1.w};
            float wza[8] = {wz0.x, wz0.y, wz0.z, wz0.w, wz1.x, wz1.y, wz1.z, wz1.w};

            short8 a;
#pragma unroll
            for (int j = 0; j < 8; ++j) {
                float h = __uint_as_float(((unsigned int)zv[kt][j]) << 16);
                h = fmaf(x, wxa[j], h);
                h = fmaf(y, wya[j], h);
                h = fmaf(z, wza[j], h);
                h = fmaxf(h, 0.01f * h);    // leaky_relu, exact both signs
                a[j] = f2bf_hw(h);
            }
#pragma unroll
            for (int nt = 0; nt < 8; ++nt) {
                short8 b = w2lds[(kt * 8 + nt) * 64 + l];   // ds_read_b128
                acc[nt] = __builtin_amdgcn_mfma_f32_16x16x32_bf16(a, b, acc[nt], 0, 0, 0);
            }
        }

        int col = l & 15;
#pragma unroll
        for (int nt = 0; nt < 8; ++nt) {
            float m = fmaxf(fmaxf(acc[nt][0], acc[nt][1]),
                            fmaxf(acc[nt][2], acc[nt][3]));
            m = fmaxf(m, __shfl_xor(m, 16));     // combine group pairs
            if (!(hi & 1)) {
                int p = tile * 2 + (hi >> 1);
                if (p < npts)
                    out[(size_t)p * EF + nt * 16 + col] = m + b2[nt * 16 + col];
            }
        }
    };

    int t = wid;
    if (t >= ntiles) return;
    fetch(t, zvA, xA, yA, zA);
    while (true) {
        // phase A: compute from A-buffers, prefetch into B
        int tn = t + stride;
        bool more = tn < ntiles;
        if (more) fetch(tn, zvB, xB, yB, zB);
        compute(t, zvA, xA, yA, zA);
        if (!more) break;
        // phase B: compute from B-buffers, prefetch into A
        int tnn = tn + stride;
        bool more2 = tnn < ntiles;
        if (more2) fetch(tnn, zvA, xA, yA, zA);
        compute(tn, zvB, xB, yB, zB);
        if (!more2) break;
        t = tnn;
    }
}

extern "C" void kernel_launch(void* const* d_in, const int* in_sizes, int n_in,
                              void* d_out, int out_size, void* d_ws, size_t ws_size,
                              hipStream_t stream) {
    const float* input   = (const float*)d_in[0];
    const int*   knn_idx = (const int*)  d_in[1];
    const float* knn_xyz = (const float*)d_in[2];
    const float* W1      = (const float*)d_in[3];
    const float* b1      = (const float*)d_in[4];
    const float* W2      = (const float*)d_in[5];
    const float* b2      = (const float*)d_in[6];
    float*       out     = (float*)d_out;

    int npts   = in_sizes[0] / EF;          // 100000
    int nedges = in_sizes[1];               // npts * 8

    // workspace layout
    unsigned short* W1p = (unsigned short*)d_ws;                  // 16384
    unsigned short* W2p = W1p + 16384;                            // 16384
    unsigned short* Z   = (unsigned short*)((char*)d_ws + 65536); // npts*128

    pack_kernel<<<128, 256, 0, stream>>>(W1, W2, W1p, W2p);

    int ztiles = (npts + 31) / 32;
    zgemm_kernel<<<(ztiles + 3) / 4, 256, 0, stream>>>(
        input, W1p, b1, Z, npts, ztiles);

    int etiles = (nedges + 15) / 16;
    int eblocks = (etiles + 7) / 8;
    if (eblocks > 1024) eblocks = 1024;     // persistent: 4 blocks/CU x 256 CU
    edge_mfma_kernel<<<eblocks, 512, 0, stream>>>(
        Z, knn_idx, knn_xyz, W2p, W1, b2, out, npts, nedges, etiles);
}

// Round 11
// 98.572 us; speedup vs baseline: 2.3899x; 2.3899x over previous
//
#include <hip/hip_runtime.h>
#include <hip/hip_bf16.h>

#define EF 128
#define KNN 8

typedef __attribute__((ext_vector_type(8)))  short          short8;
typedef __attribute__((ext_vector_type(8)))  unsigned short ushort8;
typedef __attribute__((ext_vector_type(4)))  float          f32x4;
typedef __attribute__((ext_vector_type(16))) float          f32x16;

// software round-to-nearest-even f32 -> bf16 bits (cold paths)
static __device__ __forceinline__ unsigned short f2bf(float f) {
    unsigned int x = __float_as_uint(f);
    unsigned int r = x + 0x7fffu + ((x >> 16) & 1u);
    return (unsigned short)(r >> 16);
}
// sanctioned compiler conversion (RNE) for hot paths
static __device__ __forceinline__ short f2bf_hw(float f) {
    return (short)__bfloat16_as_ushort(__float2bfloat16(f));
}

// ---------------------------------------------------------------------------
// pack_kernel:
//   W1[:128] -> W1p, 32x32x16 B-frag order (zgemm):
//     s = (((kt*4+nt)*64+l)*8+j); k = kt*16+(l>>5)*8+j; n = nt*32+(l&31)
//   W2      -> W2p, 16x16x32 B-frag order (edge kernel):
//     s = (((kt*8+nt)*64+l)*8+j); k = kt*32+(l>>4)*8+j; n = nt*16+(l&15)
// ---------------------------------------------------------------------------
__global__ __launch_bounds__(256) void pack_kernel(
    const float* __restrict__ W1, const float* __restrict__ W2,
    unsigned short* __restrict__ W1p, unsigned short* __restrict__ W2p)
{
    int t = blockIdx.x * 256 + threadIdx.x;
    if (t < 16384) {
        int s = t;
        int j  = s & 7;
        int l  = (s >> 3) & 63;
        int nt = (s >> 9) & 3;
        int kt = (s >> 11) & 7;
        int k = kt * 16 + (l >> 5) * 8 + j;
        int n = nt * 32 + (l & 31);
        W1p[s] = f2bf(W1[k * EF + n]);
    } else if (t < 32768) {
        int s = t - 16384;
        int j  = s & 7;
        int l  = (s >> 3) & 63;
        int nt = (s >> 9) & 7;
        int kt = (s >> 12) & 3;
        int k = kt * 32 + (l >> 4) * 8 + j;
        int n = nt * 16 + (l & 15);
        W2p[s] = f2bf(W2[k * EF + n]);
    }
}

// ---------------------------------------------------------------------------
// zgemm_kernel: Z[p][d] = bf16( b1[d] + sum_k input[p][k] * W1[k][d] )
// (unchanged 32x32x16 structure, verified rounds 2/5/7/8/9)
// ---------------------------------------------------------------------------
__global__ __launch_bounds__(256) void zgemm_kernel(
    const float* __restrict__ input,
    const unsigned short* __restrict__ W1p,
    const float* __restrict__ b1,
    unsigned short* __restrict__ Z,
    int npts, int ntiles)
{
    int l = threadIdx.x & 63;
    int tile = blockIdx.x * 4 + (threadIdx.x >> 6);
    if (tile >= ntiles) return;
    int p0   = tile * 32;
    int r    = l & 31;
    int half = l >> 5;
    int prow = p0 + r;
    if (prow >= npts) prow = npts - 1;      // clamp for ragged tail (reads only)
    const float* Arow = input + (size_t)prow * EF;

    f32x16 acc[4];
#pragma unroll
    for (int nt = 0; nt < 4; ++nt)
#pragma unroll
        for (int i = 0; i < 16; ++i) acc[nt][i] = 0.f;

#pragma unroll
    for (int kt = 0; kt < 8; ++kt) {
        int k0 = kt * 16 + half * 8;
        float4 a0 = *(const float4*)(Arow + k0);
        float4 a1 = *(const float4*)(Arow + k0 + 4);
        short8 a;
        a[0] = f2bf_hw(a0.x); a[1] = f2bf_hw(a0.y);
        a[2] = f2bf_hw(a0.z); a[3] = f2bf_hw(a0.w);
        a[4] = f2bf_hw(a1.x); a[5] = f2bf_hw(a1.y);
        a[6] = f2bf_hw(a1.z); a[7] = f2bf_hw(a1.w);
#pragma unroll
        for (int nt = 0; nt < 4; ++nt) {
            short8 b = *(const short8*)(W1p + ((size_t)((kt * 4 + nt) * 64 + l)) * 8);
            acc[nt] = __builtin_amdgcn_mfma_f32_32x32x16_bf16(a, b, acc[nt], 0, 0, 0);
        }
    }

    int col = l & 31;
#pragma unroll
    for (int nt = 0; nt < 4; ++nt) {
        float bb = b1[nt * 32 + col];
#pragma unroll
        for (int reg = 0; reg < 16; ++reg) {
            int row = (reg & 3) + 8 * (reg >> 2) + 4 * half;
            int p = p0 + row;
            if (p < npts)
                Z[(size_t)p * EF + nt * 32 + col] = f2bf(acc[nt][reg] + bb);
        }
    }
}

// ---------------------------------------------------------------------------
// edge_mfma_kernel (16x16x32): per wave TWO consecutive 16-edge tiles,
// software-pipelined with straight-line macro code and NAMED register
// buffers (no lambdas / array refs -> no scratch). All loads for both
// tiles issue before either compute; compute A's wait is covered by B's
// in-flight loads. W2 staged in LDS once per block (8 waves share).
// ---------------------------------------------------------------------------
#define FETCH_TILE(TILE, ZV0, ZV1, ZV2, ZV3, XX, YY, ZZ, IDX)                 \
    {                                                                          \
        int edge_ = (TILE) * 16 + r;                                           \
        if (edge_ >= nedges) edge_ = nedges - 1;                               \
        IDX = knn_idx[edge_];                                                  \
        XX = knn_xyz[edge_ * 3 + 0];                                           \
        YY = knn_xyz[edge_ * 3 + 1];                                           \
        ZZ = knn_xyz[edge_ * 3 + 2];                                           \
        const unsigned short* Zrow_ = Z + (size_t)IDX * EF;                    \
        ZV0 = *(const ushort8*)(Zrow_ + 0 * 32 + hi * 8);                      \
        ZV1 = *(const ushort8*)(Zrow_ + 1 * 32 + hi * 8);                      \
        ZV2 = *(const ushort8*)(Zrow_ + 2 * 32 + hi * 8);                      \
        ZV3 = *(const ushort8*)(Zrow_ + 3 * 32 + hi * 8);                      \
    }

#define COMPUTE_TILE(TILE, ZV0, ZV1, ZV2, ZV3, XX, YY, ZZ)                    \
    {                                                                          \
        f32x4 acc[8];                                                          \
        _Pragma("unroll")                                                      \
        for (int nt = 0; nt < 8; ++nt)                                         \
            _Pragma("unroll")                                                  \
            for (int i = 0; i < 4; ++i) acc[nt][i] = 0.f;                      \
        _Pragma("unroll")                                                      \
        for (int kt = 0; kt < 4; ++kt) {                                       \
            ushort8 zv_ = (kt == 0) ? ZV0 : (kt == 1) ? ZV1                    \
                        : (kt == 2) ? ZV2 : ZV3;                               \
            int d0 = kt * 32 + hi * 8;                                         \
            float4 wx0 = *(const float4*)&wlds[0 * EF + d0];                   \
            float4 wx1 = *(const float4*)&wlds[0 * EF + d0 + 4];               \
            float4 wy0 = *(const float4*)&wlds[1 * EF + d0];                   \
            float4 wy1 = *(const float4*)&wlds[1 * EF + d0 + 4];               \
            float4 wz0 = *(const float4*)&wlds[2 * EF + d0];                   \
            float4 wz1 = *(const float4*)&wlds[2 * EF + d0 + 4];               \
            float wxa[8] = {wx0.x, wx0.y, wx0.z, wx0.w,                        \
                            wx1.x, wx1.y, wx1.z, wx1.w};                       \
            float wya[8] = {wy0.x, wy0.y, wy0.z, wy0.w,                        \
                            wy1.x, wy1.y, wy1.z, wy1.w};                       \
            float wza[8] = {wz0.x, wz0.y, wz0.z, wz0.w,                        \
                            wz1.x, wz1.y, wz1.z, wz1.w};                       \
            short8 a;                                                          \
            _Pragma("unroll")                                                  \
            for (int j = 0; j < 8; ++j) {                                      \
                float h = __uint_as_float(((unsigned int)zv_[j]) << 16);       \
                h = fmaf(XX, wxa[j], h);                                       \
                h = fmaf(YY, wya[j], h);                                       \
                h = fmaf(ZZ, wza[j], h);                                       \
                h = fmaxf(h, 0.01f * h);                                       \
                a[j] = f2bf_hw(h);                                             \
            }                                                                  \
            _Pragma("unroll")                                                  \
            for (int nt = 0; nt < 8; ++nt) {                                   \
                short8 b = w2lds[(kt * 8 + nt) * 64 + l];                      \
                acc[nt] = __builtin_amdgcn_mfma_f32_16x16x32_bf16(             \
                    a, b, acc[nt], 0, 0, 0);                                   \
            }                                                                  \
        }                                                                      \
        int col = l & 15;                                                      \
        _Pragma("unroll")                                                      \
        for (int nt = 0; nt < 8; ++nt) {                                       \
            float m = fmaxf(fmaxf(acc[nt][0], acc[nt][1]),                     \
                            fmaxf(acc[nt][2], acc[nt][3]));                    \
            m = fmaxf(m, __shfl_xor(m, 16));                                   \
            if (!(hi & 1)) {                                                   \
                int p = (TILE) * 2 + (hi >> 1);                                \
                if (p < npts)                                                  \
                    out[(size_t)p * EF + nt * 16 + col] = m + b2[nt * 16 + col];\
            }                                                                  \
        }                                                                      \
    }

__global__ __launch_bounds__(512) void edge_mfma_kernel(
    const unsigned short* __restrict__ Z,
    const int* __restrict__ knn_idx,
    const float* __restrict__ knn_xyz,
    const unsigned short* __restrict__ W2p,
    const float* __restrict__ W1,       // xyz rows at +128*EF (f32)
    const float* __restrict__ b2,
    float* __restrict__ out,
    int npts, int nedges, int ntiles)
{
    __shared__ short8 w2lds[2048];      // 32 KB: full packed W2, frag order
    __shared__ float  wlds[3 * EF];     // W1 rows 128..130, f32

    // ---- stage W2 fragments + xyz weights into LDS (once per block) -------
    {
        const short8* W2v = (const short8*)W2p;
#pragma unroll
        for (int i = threadIdx.x; i < 2048; i += 512)
            w2lds[i] = W2v[i];
        for (int t = threadIdx.x; t < 3 * EF; t += 512)
            wlds[t] = W1[EF * EF + t];
    }
    __syncthreads();

    int l  = threadIdx.x & 63;
    int r  = l & 15;                    // edge row within tile
    int hi = l >> 4;                    // k-group 0..3
    int wid = blockIdx.x * 8 + (threadIdx.x >> 6);

    int tA = wid * 2;                   // two consecutive tiles per wave
    int tB = tA + 1;
    if (tA >= ntiles) return;
    bool haveB = tB < ntiles;

    ushort8 zA0, zA1, zA2, zA3, zB0, zB1, zB2, zB3;
    float xA, yA, zAx, xB, yB, zBx;
    int iA, iB;

    FETCH_TILE(tA, zA0, zA1, zA2, zA3, xA, yA, zAx, iA);
    if (haveB) FETCH_TILE(tB, zB0, zB1, zB2, zB3, xB, yB, zBx, iB);

    COMPUTE_TILE(tA, zA0, zA1, zA2, zA3, xA, yA, zAx);
    if (haveB) COMPUTE_TILE(tB, zB0, zB1, zB2, zB3, xB, yB, zBx);
}

extern "C" void kernel_launch(void* const* d_in, const int* in_sizes, int n_in,
                              void* d_out, int out_size, void* d_ws, size_t ws_size,
                              hipStream_t stream) {
    const float* input   = (const float*)d_in[0];
    const int*   knn_idx = (const int*)  d_in[1];
    const float* knn_xyz = (const float*)d_in[2];
    const float* W1      = (const float*)d_in[3];
    const float* b1      = (const float*)d_in[4];
    const float* W2      = (const float*)d_in[5];
    const float* b2      = (const float*)d_in[6];
    float*       out     = (float*)d_out;

    int npts   = in_sizes[0] / EF;          // 100000
    int nedges = in_sizes[1];               // npts * 8

    // workspace layout
    unsigned short* W1p = (unsigned short*)d_ws;                  // 16384
    unsigned short* W2p = W1p + 16384;                            // 16384
    unsigned short* Z   = (unsigned short*)((char*)d_ws + 65536); // npts*128

    pack_kernel<<<128, 256, 0, stream>>>(W1, W2, W1p, W2p);

    int ztiles = (npts + 31) / 32;
    zgemm_kernel<<<(ztiles + 3) / 4, 256, 0, stream>>>(
        input, W1p, b1, Z, npts, ztiles);

    int etiles = (nedges + 15) / 16;
    int eblocks = (etiles + 15) / 16;       // 16 tiles per block (8 waves x 2)
    edge_mfma_kernel<<<eblocks, 512, 0, stream>>>(
        Z, knn_idx, knn_xyz, W2p, W1, b2, out, npts, nedges, etiles);
}